// Round 1
// 206.483 us; speedup vs baseline: 1.0220x; 1.0220x over previous
//
#include <hip/hip_runtime.h>
#include <hip/hip_bf16.h>
#include <stdint.h>
#include <math.h>

// PANConcDQL round 18 -- math identical to r17 (passed, absmax 0.0).
// Change: split r17_poolgat (44us, occupancy 9.4%, VALU 16% -> latency-bound,
// 8x-duplicated preamble per graph) into:
//   r18_pool: 16 blocks, preamble ONCE per graph (float4 rank scan), stages
//             xp/xl/kidx/RT-transpose to workspace (coalesced).
//   r18_gat : (16,52) blocks, one wave per output row, no LDS, coalesced reads.
// Per-row math + reduction order kept instruction-identical (bit-exact).
#define BB   16
#define NPn  512
#define LLp  20
#define NAa  50
#define KKk  410
#define NNt  (BB * NPn)   // 8192
#define EEe  (6 * NNt)    // 49152
#define NFf  13
#define KPAD 416
#define KP2  448          // padded GAT staging width (7*64)
#define EPSf 1e-5f
#define QCLMP 1e6f
#define MAXD 28
#define PADR 512

__device__ __forceinline__ float r17_sane(float v) {
    if (!(v == v)) return 0.0f;
    return fminf(fmaxf(v, -1e15f), 1e15f);
}

// ---------------------------------------------------------------------------
// K1: edge scatter -> global bitsets (one edge per thread, 192 blocks).
__global__ __launch_bounds__(256) void r17_scatter(
    const int* __restrict__ ei,
    uint32_t* __restrict__ fwdb, uint32_t* __restrict__ trsb)
{
    const int e = blockIdx.x * 256 + threadIdx.x;
    if (e < EEe) {
        const int src = ei[e], dst = ei[EEe + e];
        atomicOr(&fwdb[(size_t)dst * 16 + ((src & 511) >> 5)], 1u << (src & 31));
        atomicOr(&trsb[(size_t)src * 16 + ((dst & 511) >> 5)], 1u << (dst & 31));
    }
}

// ---------------------------------------------------------------------------
// K2: bitset -> CSR planes (u16, csr[j*8192+node], coalesced stores).
__global__ __launch_bounds__(256) void r17_extract(
    const uint32_t* __restrict__ fwdb, const uint32_t* __restrict__ trsb,
    unsigned short* __restrict__ csrF, unsigned short* __restrict__ csrT)
{
    const int t = blockIdx.x * 256 + threadIdx.x;      // 0..16383
    const int node = t & 8191;
    const uint32_t* bs = (t < 8192) ? (fwdb + (size_t)node * 16)
                                    : (trsb + (size_t)node * 16);
    unsigned short* cs = (t < 8192) ? csrF : csrT;
    int cnt = 0;
    for (int w = 0; w < 16; ++w) {
        uint32_t bits = bs[w];
        while (bits) {
            const int u = (w << 5) + __ffs(bits) - 1;
            bits &= bits - 1;
            if (cnt < MAXD) cs[(size_t)cnt * 8192 + node] = (unsigned short)u;
            ++cnt;
        }
    }
    for (int j = cnt; j < MAXD; ++j) cs[(size_t)j * 8192 + node] = PADR;
}

// ---------------------------------------------------------------------------
// K3: mid, grid (16,20) x 512 (r15_mid verbatim).
__global__ __launch_bounds__(512) void r17_mid(
    const float* __restrict__ x,
    const unsigned short* __restrict__ csrF,
    const unsigned short* __restrict__ csrT,
    const float* __restrict__ panw,
    const float* __restrict__ l1w, const float* __restrict__ l1b,
    float* __restrict__ h_raw, float* __restrict__ colsum,
    uint32_t* __restrict__ Rb)
{
    __shared__ __align__(16) uint32_t sbuf[1047];
    float* pa  = (float*)sbuf;             // 513
    float* pb  = (float*)(sbuf + 513);     // 513
    float* wsh = (float*)(sbuf + 1026);    // 21
    const int b = blockIdx.x, y = blockIdx.y, t = threadIdx.x;
    const int node = b * 512 + t;

    if (y < 4) {
        const int c = y;
        int iF[MAXD];
#pragma unroll
        for (int j = 0; j < MAXD; ++j) iF[j] = (int)csrF[(size_t)j * 8192 + node];
        if (t < 21) wsh[t] = panw[t];

        pa[t] = 1.0f;
        if (t == 0) { pa[512] = 0.0f; pb[512] = 0.0f; }
        __syncthreads();
        float dacc = wsh[0];
        {
            float* rp = pa; float* rn = pb;
            for (int i = 1; i <= LLp; ++i) {
                float tv[MAXD];
#pragma unroll
                for (int j = 0; j < MAXD; ++j) tv[j] = rp[iF[j]];
                float s = 0.0f;
#pragma unroll
                for (int j = 0; j < MAXD; ++j) s += tv[j];
                rn[t] = s;
                dacc += wsh[i] * s;
                __syncthreads();
                float* tp = rp; rp = rn; rn = tp;
            }
        }
        const float d0 = (dacc > 0.0f) ? 1.0f / sqrtf(dacc) : 0.0f;

        int idx[MAXD];
        if (c == 3) {
#pragma unroll
            for (int j = 0; j < MAXD; ++j) idx[j] = (int)csrT[(size_t)j * 8192 + node];
        } else {
#pragma unroll
            for (int j = 0; j < MAXD; ++j) idx[j] = iF[j];
        }
        float seed;
        if (c < 3) {
            float xw = 0.0f;
            const float* xr = x + (size_t)node * NFf;
            for (int f = 0; f < NFf; ++f) xw += xr[f] * l1w[f * 3 + c];
            seed = d0 * xw;
        } else {
            seed = d0;
        }
        pa[t] = seed;
        if (t == 0) { pa[512] = 0.0f; pb[512] = 0.0f; }
        __syncthreads();
        float acc = wsh[0] * seed;
        {
            float* rp = pa; float* rn = pb;
            for (int i = 1; i <= LLp; ++i) {
                float tv[MAXD];
#pragma unroll
                for (int j = 0; j < MAXD; ++j) tv[j] = rp[idx[j]];
                float s = 0.0f;
#pragma unroll
                for (int j = 0; j < MAXD; ++j) s += tv[j];
                rn[t] = s;
                acc += wsh[i] * s;
                __syncthreads();
                float* tp = rp; rp = rn; rn = tp;
            }
        }
        if (c < 3) h_raw[(size_t)node * 3 + c] = r17_sane(d0 * acc + l1b[c]);
        else       colsum[node] = r17_sane(d0 * acc);
    } else {
        const int q = y - 4;
        int iF[MAXD];
#pragma unroll
        for (int j = 0; j < MAXD; ++j) iF[j] = (int)csrF[(size_t)j * 8192 + node];
        uint32_t* R1 = sbuf;
        uint32_t* R2 = sbuf + 513;
        R1[t] = ((t >> 5) == q) ? (1u << (t & 31)) : 0u;
        if (t == 0) { R1[512] = 0u; R2[512] = 0u; }
        __syncthreads();
        uint32_t* Rp = R1; uint32_t* Rn = R2;
        for (int i = 0; i < LLp; ++i) {
            uint32_t tv[MAXD];
#pragma unroll
            for (int j = 0; j < MAXD; ++j) tv[j] = Rp[iF[j]];
            uint32_t r = Rp[t];
#pragma unroll
            for (int j = 0; j < MAXD; ++j) r |= tv[j];
            Rn[t] = r;
            __syncthreads();
            uint32_t* tp = Rp; Rp = Rn; Rn = tp;
        }
        Rb[(size_t)node * 16 + q] = Rp[t];
    }
}

// ---------------------------------------------------------------------------
// K4a: pool -- grid 16 x 512. GraphNorm stats + score + top-K rank + staging,
// executed ONCE per graph (was 8x duplicated inside r17_poolgat).
__global__ __launch_bounds__(512) void r18_pool(
    const float* __restrict__ h_raw,
    const float* __restrict__ colsum,
    const uint32_t* __restrict__ Rb,
    const float* n1w, const float* n1b, const float* n1ms,
    const float* poolp, const float* poolb,
    const float* gwl, const float* gbl,
    float* __restrict__ x1,
    float* __restrict__ xpg,      // [BB][KPAD][3]
    float* __restrict__ xlg,      // [BB][KP2][3]  (pads zeroed)
    int*   __restrict__ kidxg,    // [BB][KPAD]
    uint32_t* __restrict__ RTg)   // [BB][16][KP2] (pads zeroed)
{
    __shared__ __align__(16) uint32_t pg[2208];
    float* sc   = (float*)pg;                  // 512
    float* mv   = (float*)(pg + 512);          // 8
    float* wred = (float*)(pg + 520);          // 24
    float* xpS  = (float*)(pg + 544);          // 1248 (416*3)
    int*   kidx = (int*)(pg + 1792);           // 416
    const int b = blockIdx.x, t = threadIdx.x;
    const int lane = t & 63, wv = t >> 6;
    const float inv_n = 1.0f / (float)NNt;

    // --- global GraphNorm stats (identical instruction sequence to r17) ---
    float hv0[16], hv1[16], hv2[16];
    float p0 = 0.0f, p1 = 0.0f, p2 = 0.0f;
#pragma unroll
    for (int k = 0; k < 16; ++k) {
        const float* hr = h_raw + (size_t)(k * 512 + t) * 3;
        hv0[k] = hr[0]; hv1[k] = hr[1]; hv2[k] = hr[2];
        p0 += hv0[k]; p1 += hv1[k]; p2 += hv2[k];
    }
#pragma unroll
    for (int off = 32; off; off >>= 1) {
        p0 += __shfl_xor(p0, off); p1 += __shfl_xor(p1, off); p2 += __shfl_xor(p2, off);
    }
    if (lane == 0) { wred[wv * 3 + 0] = p0; wred[wv * 3 + 1] = p1; wred[wv * 3 + 2] = p2; }
    __syncthreads();
    if (t < 3) {
        float s = 0.0f;
        for (int w = 0; w < 8; ++w) s += wred[w * 3 + t];
        mv[t] = s * inv_n;
    }
    __syncthreads();
    const float mm0 = n1ms[0] * mv[0], mm1 = n1ms[1] * mv[1], mm2 = n1ms[2] * mv[2];
    float q0 = 0.0f, q1 = 0.0f, q2 = 0.0f;
#pragma unroll
    for (int k = 0; k < 16; ++k) {
        const float d0 = hv0[k] - mm0, d1 = hv1[k] - mm1, d2 = hv2[k] - mm2;
        q0 += d0 * d0; q1 += d1 * d1; q2 += d2 * d2;
    }
#pragma unroll
    for (int off = 32; off; off >>= 1) {
        q0 += __shfl_xor(q0, off); q1 += __shfl_xor(q1, off); q2 += __shfl_xor(q2, off);
    }
    if (lane == 0) { wred[wv * 3 + 0] = q0; wred[wv * 3 + 1] = q1; wred[wv * 3 + 2] = q2; }
    __syncthreads();
    if (t < 3) {
        float s = 0.0f;
        for (int w = 0; w < 8; ++w) s += wred[w * 3 + t];
        mv[3 + t] = s * inv_n;
    }
    __syncthreads();

    // --- norm + relu + x1 write + pooling score ---
    const float mmv[3] = { mm0, mm1, mm2 };
    float xv[3];
#pragma unroll
    for (int c = 0; c < 3; ++c) {
        const float iv = 1.0f / sqrtf(fmaxf(mv[3 + c], 0.0f) + EPSf);
        const float o  = h_raw[(size_t)(b * NPn + t) * 3 + c] - mmv[c];
        const float tt = n1w[c] * o * iv + n1b[c];
        xv[c] = fmaxf(tt, 0.0f);
        x1[(size_t)(b * NPn + t) * 3 + c] = xv[c];
    }
    float s = poolb[0] * (xv[0] * poolp[0] + xv[1] * poolp[1] + xv[2] * poolp[2])
            + poolb[1] * colsum[b * NPn + t];
    s = tanhf(s);
    if (!(s == s)) s = 0.0f;
    sc[t] = s;
    __syncthreads();

    // --- rank count (float4 LDS reads: 128 iters instead of 512) ---
    int cnt = 0;
    for (int u = 0; u < NPn; u += 4) {
        const float4 s4 = *(const float4*)(sc + u);
        cnt += ((s4.x > s) || (s4.x == s && (u + 0) < t)) ? 1 : 0;
        cnt += ((s4.y > s) || (s4.y == s && (u + 1) < t)) ? 1 : 0;
        cnt += ((s4.z > s) || (s4.z == s && (u + 2) < t)) ? 1 : 0;
        cnt += ((s4.w > s) || (s4.w == s && (u + 3) < t)) ? 1 : 0;
    }
    if (cnt < KKk) {                       // rank-count bijection
        const float xp0 = xv[0] * s, xp1 = xv[1] * s, xp2 = xv[2] * s;
        kidx[cnt] = t;
        xpS[cnt * 3 + 0] = xp0;
        xpS[cnt * 3 + 1] = xp1;
        xpS[cnt * 3 + 2] = xp2;
        kidxg[b * KPAD + cnt] = t;
        xpg[(size_t)(b * KPAD + cnt) * 3 + 0] = xp0;
        xpg[(size_t)(b * KPAD + cnt) * 3 + 1] = xp1;
        xpg[(size_t)(b * KPAD + cnt) * 3 + 2] = xp2;
    }
    __syncthreads();

    // --- stage xl (=xp@Wl+bl) and transposed reachability planes to global ---
    float Wl[9];
#pragma unroll
    for (int i2 = 0; i2 < 9; ++i2) Wl[i2] = gwl[i2];
    const float Bl0 = gbl[0], Bl1 = gbl[1], Bl2 = gbl[2];
    if (t < KP2) {
        float xl0, xl1, xl2;
        uint32_t* RT = RTg + (size_t)b * 16 * KP2 + t;
        if (t < KKk) {
            const float c0 = xpS[t * 3 + 0];
            const float c1 = xpS[t * 3 + 1];
            const float c2 = xpS[t * 3 + 2];
            xl0 = c0 * Wl[0] + c1 * Wl[3] + c2 * Wl[6] + Bl0;
            xl1 = c0 * Wl[1] + c1 * Wl[4] + c2 * Wl[7] + Bl1;
            xl2 = c0 * Wl[2] + c1 * Wl[5] + c2 * Wl[8] + Bl2;
            const uint4* rr = (const uint4*)(Rb + (size_t)(b * NPn + kidx[t]) * 16);
            const uint4 r0 = rr[0], r1 = rr[1], r2 = rr[2], r3 = rr[3];
            RT[ 0 * KP2] = r0.x; RT[ 1 * KP2] = r0.y; RT[ 2 * KP2] = r0.z; RT[ 3 * KP2] = r0.w;
            RT[ 4 * KP2] = r1.x; RT[ 5 * KP2] = r1.y; RT[ 6 * KP2] = r1.z; RT[ 7 * KP2] = r1.w;
            RT[ 8 * KP2] = r2.x; RT[ 9 * KP2] = r2.y; RT[10 * KP2] = r2.z; RT[11 * KP2] = r2.w;
            RT[12 * KP2] = r3.x; RT[13 * KP2] = r3.y; RT[14 * KP2] = r3.z; RT[15 * KP2] = r3.w;
        } else {
            xl0 = 0.0f; xl1 = 0.0f; xl2 = 0.0f;
#pragma unroll
            for (int w = 0; w < 16; ++w) RT[w * KP2] = 0u;
        }
        xlg[(size_t)(b * KP2 + t) * 3 + 0] = xl0;
        xlg[(size_t)(b * KP2 + t) * 3 + 1] = xl1;
        xlg[(size_t)(b * KP2 + t) * 3 + 2] = xl2;
    }
}

// ---------------------------------------------------------------------------
// K4b: GAT -- grid (16,52) x 512, one wave per output row, no LDS.
// Per-row loop + butterfly identical to r17 (bit-exact).
__global__ __launch_bounds__(512) void r18_gat(
    const float* __restrict__ xpg,
    const float* __restrict__ xlg,
    const int* __restrict__ kidxg,
    const uint32_t* __restrict__ RTg,
    const float* __restrict__ gwr, const float* __restrict__ gbr,
    const float* __restrict__ gatt, const float* __restrict__ gbias,
    float* __restrict__ g_raw)
{
    const int b = blockIdx.x, y = blockIdx.y, t = threadIdx.x;
    const int lane = t & 63, wv = t >> 6;
    const int i = y * 8 + wv;                  // row of this wave
    if (i >= KKk) return;

    float Wr[9];
#pragma unroll
    for (int k = 0; k < 9; ++k) Wr[k] = gwr[k];
    const float Br0 = gbr[0], Br1 = gbr[1], Br2 = gbr[2];
    const float At0 = gatt[0], At1 = gatt[1], At2 = gatt[2];
    const float Gb0 = gbias[0], Gb1 = gbias[1], Gb2 = gbias[2];

    const int bi = kidxg[b * KPAD + i];
    const float c0 = xpg[(size_t)(b * KPAD + i) * 3 + 0];
    const float c1 = xpg[(size_t)(b * KPAD + i) * 3 + 1];
    const float c2 = xpg[(size_t)(b * KPAD + i) * 3 + 2];
    const float xr0 = c0 * Wr[0] + c1 * Wr[3] + c2 * Wr[6] + Br0;
    const float xr1 = c0 * Wr[1] + c1 * Wr[4] + c2 * Wr[7] + Br1;
    const float xr2 = c0 * Wr[2] + c1 * Wr[5] + c2 * Wr[8] + Br2;

    const uint32_t mbit = 1u << (bi & 31);
    const uint32_t* Rw = RTg + (size_t)(b * 16 + (bi >> 5)) * KP2;
    const float* xlb = xlg + (size_t)b * KP2 * 3;

    float mx = -3e38f, lsum = 0.0f, b0 = 0.0f, b1 = 0.0f, b2 = 0.0f;
#pragma unroll
    for (int it = 0; it < 7; ++it) {
        const int j = lane + it * 64;          // < 448, coalesced
        const uint32_t rw = Rw[j];
        const float xl0 = xlb[j * 3 + 0];
        const float xl1 = xlb[j * 3 + 1];
        const float xl2 = xlb[j * 3 + 2];
        const bool valid = (rw & mbit) || (j == i);   // pads auto-invalid
        float e0 = xr0 + xl0; e0 = e0 > 0.0f ? e0 : 0.2f * e0;
        float e1 = xr1 + xl1; e1 = e1 > 0.0f ? e1 : 0.2f * e1;
        float e2 = xr2 + xl2; e2 = e2 > 0.0f ? e2 : 0.2f * e2;
        const float sv = At0 * e0 + At1 * e1 + At2 * e2;
        if (valid) {
            if (sv > mx) {
                const float r = __expf(mx - sv);
                lsum *= r; b0 *= r; b1 *= r; b2 *= r;
                mx = sv;
            }
            const float pj = __expf(sv - mx);
            lsum += pj;
            b0 += pj * xl0; b1 += pj * xl1; b2 += pj * xl2;
        }
    }
#pragma unroll
    for (int off = 32; off; off >>= 1) {       // butterfly LSE merge
        const float mo = __shfl_xor(mx, off);
        const float lo = __shfl_xor(lsum, off);
        const float d0 = __shfl_xor(b0, off);
        const float d1 = __shfl_xor(b1, off);
        const float d2 = __shfl_xor(b2, off);
        const float M  = fmaxf(mx, mo);
        const float ea = __expf(mx - M), eb = __expf(mo - M);
        lsum = lsum * ea + lo * eb;
        b0 = b0 * ea + d0 * eb;
        b1 = b1 * ea + d1 * eb;
        b2 = b2 * ea + d2 * eb;
        mx = M;
    }
    if (lane == 0) {
        const float rl = 1.0f / fmaxf(lsum, 1e-30f);
        g_raw[(size_t)(b * KPAD + i) * 3 + 0] = r17_sane(b0 * rl + Gb0);
        g_raw[(size_t)(b * KPAD + i) * 3 + 1] = r17_sane(b1 * rl + Gb1);
        g_raw[(size_t)(b * KPAD + i) * 3 + 2] = r17_sane(b2 * rl + Gb2);
    }
}

// ---------------------------------------------------------------------------
// K5: head (r16 version: shfl stats).
__global__ __launch_bounds__(512) void r17_head(
    const float* __restrict__ g_raw,
    const float* __restrict__ x1,
    const float* __restrict__ x,
    const int* __restrict__ cnid,
    const int* __restrict__ amask,
    const float* n2w, const float* n2b, const float* n2ms,
    const float* v1w, const float* v1b,
    const float* v2w, const float* v2b,
    const float* v3w, const float* v3b,
    const float* a1w, const float* a1b,
    const float* a2w, const float* a2b,
    const float* a3w, const float* a3b,
    float* __restrict__ out)
{
    __shared__ float wred[24];
    __shared__ float mv[6];
    __shared__ float gp[3];
    __shared__ float feat[19];
    __shared__ float h1a[10], h1v[10], h2a[5], h2v[5];
    __shared__ float a3[50];
    __shared__ float vout_s, amean_s;
    const int b = blockIdx.x, t = threadIdx.x;
    const int lane = t & 63, wv = t >> 6;
    const float denom = 1.0f / (float)(BB * KKk);

    float gv0[13], gv1[13], gv2[13];
    float p0 = 0.0f, p1 = 0.0f, p2 = 0.0f;
#pragma unroll
    for (int k = 0; k < 13; ++k) {
        const int r = k * 512 + t;
        float q0 = 0.0f, q1 = 0.0f, q2 = 0.0f;
        if (r < BB * KKk) {
            const int bq = r / KKk, iq = r - bq * KKk;
            const float* gr = g_raw + (size_t)(bq * KPAD + iq) * 3;
            q0 = gr[0]; q1 = gr[1]; q2 = gr[2];
        }
        gv0[k] = q0; gv1[k] = q1; gv2[k] = q2;
        p0 += q0; p1 += q1; p2 += q2;
    }
#pragma unroll
    for (int off = 32; off; off >>= 1) {
        p0 += __shfl_xor(p0, off); p1 += __shfl_xor(p1, off); p2 += __shfl_xor(p2, off);
    }
    if (lane == 0) { wred[wv * 3 + 0] = p0; wred[wv * 3 + 1] = p1; wred[wv * 3 + 2] = p2; }
    __syncthreads();
    if (t < 3) {
        float s = 0.0f;
        for (int w = 0; w < 8; ++w) s += wred[w * 3 + t];
        mv[t] = s * denom;
    }
    __syncthreads();
    const float mm0 = n2ms[0] * mv[0], mm1 = n2ms[1] * mv[1], mm2 = n2ms[2] * mv[2];
    float q0a = 0.0f, q1a = 0.0f, q2a = 0.0f;
#pragma unroll
    for (int k = 0; k < 13; ++k) {
        const int r = k * 512 + t;
        if (r < BB * KKk) {
            const float d0 = gv0[k] - mm0, d1 = gv1[k] - mm1, d2 = gv2[k] - mm2;
            q0a += d0 * d0; q1a += d1 * d1; q2a += d2 * d2;
        }
    }
#pragma unroll
    for (int off = 32; off; off >>= 1) {
        q0a += __shfl_xor(q0a, off); q1a += __shfl_xor(q1a, off); q2a += __shfl_xor(q2a, off);
    }
    if (lane == 0) { wred[wv * 3 + 0] = q0a; wred[wv * 3 + 1] = q1a; wred[wv * 3 + 2] = q2a; }
    __syncthreads();
    if (t < 3) {
        float s = 0.0f;
        for (int w = 0; w < 8; ++w) s += wred[w * 3 + t];
        mv[3 + t] = s * denom;
    }
    __syncthreads();

    const float mmv[3] = { mm0, mm1, mm2 };
    float s3[3] = { 0.0f, 0.0f, 0.0f };
    if (t < KKk) {
        const size_t r = (size_t)(b * KPAD + t) * 3;
#pragma unroll
        for (int c = 0; c < 3; ++c) {
            const float iv = 1.0f / sqrtf(fmaxf(mv[3 + c], 0.0f) + EPSf);
            s3[c] = fmaxf((g_raw[r + c] - mmv[c]) * iv * n2w[c] + n2b[c], 0.0f);
        }
    }
    float g0 = s3[0], g1 = s3[1], g2 = s3[2];
#pragma unroll
    for (int off = 32; off; off >>= 1) {
        g0 += __shfl_xor(g0, off); g1 += __shfl_xor(g1, off); g2 += __shfl_xor(g2, off);
    }
    if (lane == 0) { wred[wv * 3 + 0] = g0; wred[wv * 3 + 1] = g1; wred[wv * 3 + 2] = g2; }
    __syncthreads();
    if (t < 3) {
        float s = 0.0f;
        for (int w = 0; w < 8; ++w) s += wred[w * 3 + t];
        gp[t] = s;
    }
    __syncthreads();

    if (t < 19) {
        const int gidx = cnid[b] + b * KKk;        // faithful: pooled-K offsets
        float fv;
        if (t < 13)      fv = x[(size_t)gidx * NFf + t];
        else if (t < 16) fv = x1[(size_t)gidx * 3 + (t - 13)];
        else             fv = gp[t - 16];
        feat[t] = fv;
    }
    __syncthreads();

    if (t < 10) {
        float s = a1b[t];
        for (int f = 0; f < 19; ++f) s += feat[f] * a1w[f * 10 + t];
        h1a[t] = fmaxf(s, 0.0f);
    } else if (t >= 64 && t < 74) {
        const int j = t - 64;
        float s = v1b[j];
        for (int f = 0; f < 19; ++f) s += feat[f] * v1w[f * 10 + j];
        h1v[j] = fmaxf(s, 0.0f);
    }
    __syncthreads();
    if (t < 5) {
        float s = a2b[t];
        for (int k = 0; k < 10; ++k) s += h1a[k] * a2w[k * 5 + t];
        h2a[t] = fmaxf(s, 0.0f);
    } else if (t >= 64 && t < 69) {
        const int j = t - 64;
        float s = v2b[j];
        for (int k = 0; k < 10; ++k) s += h1v[k] * v2w[k * 5 + j];
        h2v[j] = fmaxf(s, 0.0f);
    }
    __syncthreads();
    if (t < 50) {
        float s = a3b[t];
        for (int k = 0; k < 5; ++k) s += h2a[k] * a3w[k * 50 + t];
        a3[t] = s;
    } else if (t == 64) {
        float s = v3b[0];
        for (int k = 0; k < 5; ++k) s += h2v[k] * v3w[k];
        vout_s = s;
    }
    __syncthreads();
    if (t == 0) {
        float s = 0.0f;
        for (int k = 0; k < 50; ++k) s += a3[k];
        amean_s = s * (1.0f / 50.0f);
    }
    __syncthreads();
    if (t < 50) {
        float q = vout_s + a3[t] - amean_s;
        if (!(q == q)) q = 0.0f;
        q = fminf(fmaxf(q, -QCLMP), QCLMP);
        out[b * NAa + t] = (amask[b * NAa + t] == 0) ? -1e8f : q;   // FP32
    }
}

// ---------------------------------------------------------------------------
extern "C" void kernel_launch(void* const* d_in, const int* in_sizes, int n_in,
                              void* d_out, int out_size, void* d_ws, size_t ws_size,
                              hipStream_t stream) {
    (void)in_sizes; (void)n_in; (void)out_size;
    const float* x     = (const float*)d_in[0];
    const int* ei      = (const int*)d_in[1];
    const int* cnid    = (const int*)d_in[4];
    const int* amask   = (const int*)d_in[5];
    const float* panw  = (const float*)d_in[6];
    const float* l1w   = (const float*)d_in[7];
    const float* l1b   = (const float*)d_in[8];
    const float* n1w   = (const float*)d_in[9];
    const float* n1b   = (const float*)d_in[10];
    const float* n1ms  = (const float*)d_in[11];
    const float* poolp = (const float*)d_in[12];
    const float* poolb = (const float*)d_in[13];
    const float* gwl   = (const float*)d_in[14];
    const float* gbl   = (const float*)d_in[15];
    const float* gwr   = (const float*)d_in[16];
    const float* gbr   = (const float*)d_in[17];
    const float* gatt  = (const float*)d_in[18];
    const float* gbias = (const float*)d_in[19];
    const float* n2w   = (const float*)d_in[20];
    const float* n2b   = (const float*)d_in[21];
    const float* n2ms  = (const float*)d_in[22];
    const float* v1w   = (const float*)d_in[23];
    const float* v1b   = (const float*)d_in[24];
    const float* v2w   = (const float*)d_in[25];
    const float* v2b   = (const float*)d_in[26];
    const float* v3w   = (const float*)d_in[27];
    const float* v3b   = (const float*)d_in[28];
    const float* a1w   = (const float*)d_in[29];
    const float* a1b   = (const float*)d_in[30];
    const float* a2w   = (const float*)d_in[31];
    const float* a2b   = (const float*)d_in[32];
    const float* a3w   = (const float*)d_in[33];
    const float* a3b   = (const float*)d_in[34];
    float* out         = (float*)d_out;

    // ws layout (bytes): fwdb 512K | trsb 512K | Rb 512K | csrF | csrT |
    //                    h_raw | x1 | colsum | g_raw | xpg | xlg | kidxg | RTg
    uint8_t* wsb = (uint8_t*)d_ws;
    uint32_t* fwdb = (uint32_t*)wsb;
    uint32_t* trsb = (uint32_t*)(wsb + 524288);
    uint32_t* Rb   = (uint32_t*)(wsb + 1048576);
    unsigned short* csrF = (unsigned short*)(wsb + 1572864);
    unsigned short* csrT = csrF + (size_t)MAXD * 8192;
    float* h_raw  = (float*)(csrT + (size_t)MAXD * 8192);
    float* x1     = h_raw + (size_t)NNt * 3;
    float* colsum = x1 + (size_t)NNt * 3;
    float* g_raw  = colsum + NNt;
    float* xpg    = g_raw + (size_t)BB * KPAD * 3;
    float* xlg    = xpg + (size_t)BB * KPAD * 3;
    int*   kidxg  = (int*)(xlg + (size_t)BB * KP2 * 3);
    uint32_t* RTg = (uint32_t*)(kidxg + (size_t)BB * KPAD);
    const size_t needed = 1572864                              // bitsets + Rb
                        + 2 * (size_t)MAXD * 8192 * 2          // csrF + csrT
                        + ((size_t)(2 * NNt * 3 + NNt          // h_raw, x1, colsum
                           + 2 * BB * KPAD * 3                 // g_raw, xpg
                           + BB * KP2 * 3)) * 4                // xlg
                        + (size_t)BB * KPAD * 4                // kidxg
                        + (size_t)BB * 16 * KP2 * 4;           // RTg
    if (ws_size < needed) return;

    hipMemsetAsync(fwdb, 0, 1048576, stream);            // both bitsets
    r17_scatter<<<dim3((EEe + 255) / 256), dim3(256), 0, stream>>>(ei, fwdb, trsb);
    r17_extract<<<dim3(64), dim3(256), 0, stream>>>(fwdb, trsb, csrF, csrT);
    r17_mid<<<dim3(16, 20), dim3(512), 0, stream>>>(x, csrF, csrT, panw, l1w, l1b,
                                                    h_raw, colsum, Rb);
    r18_pool<<<dim3(16), dim3(512), 0, stream>>>(h_raw, colsum, Rb,
                                                 n1w, n1b, n1ms, poolp, poolb,
                                                 gwl, gbl,
                                                 x1, xpg, xlg, kidxg, RTg);
    r18_gat<<<dim3(16, 52), dim3(512), 0, stream>>>(xpg, xlg, kidxg, RTg,
                                                    gwr, gbr, gatt, gbias, g_raw);
    r17_head<<<dim3(16), dim3(512), 0, stream>>>(g_raw, x1, x, cnid, amask,
                                                 n2w, n2b, n2ms, v1w, v1b, v2w, v2b, v3w, v3b,
                                                 a1w, a1b, a2w, a2b, a3w, a3b, out);
}

// Round 2
// 201.617 us; speedup vs baseline: 1.0467x; 1.0241x over previous
//
#include <hip/hip_runtime.h>
#include <hip/hip_bf16.h>
#include <stdint.h>
#include <math.h>

// PANConcDQL round 19 -- math identical to r18 (passed, absmax 0.0).
// r18 counters: top dispatch = harness ws re-poison fill (~40us, fixed floor).
// This round attacks r17_mid (est. 40-60us, the largest OUR kernel):
//  1. dynamic-degree gathers: wave-max real degree (~13-16) instead of MAXD=28
//     -> ~45% fewer LDS gather instructions. Chunked 4-wide with compile-time
//     register indices + wave-uniform early-exit (no scratch spill).
//     FP summation order of real entries preserved (trailing +0.0 drops only).
//  2. reachability planes paired as uint2 (ds_read_b64): 8 blocks/graph, grid
//     (16,20)->(16,12)=192 blocks -> single CU round.
//  3. xlg staged as float4 -> r19_gat loads xl with one dwordx4.
#define BB   16
#define NPn  512
#define LLp  20
#define NAa  50
#define KKk  410
#define NNt  (BB * NPn)   // 8192
#define EEe  (6 * NNt)    // 49152
#define NFf  13
#define KPAD 416
#define KP2  448          // padded GAT staging width (7*64)
#define EPSf 1e-5f
#define QCLMP 1e6f
#define MAXD 28
#define PADR 512

__device__ __forceinline__ float r17_sane(float v) {
    if (!(v == v)) return 0.0f;
    return fminf(fmaxf(v, -1e15f), 1e15f);
}

// wave-max of per-thread real degree (pads are PADR).
__device__ __forceinline__ int r19_wmaxdeg(const int (&iF)[MAXD]) {
    int deg = 0;
#pragma unroll
    for (int j = 0; j < MAXD; ++j) deg += (iF[j] != PADR) ? 1 : 0;
#pragma unroll
    for (int off = 32; off; off >>= 1) {
        const int o = __shfl_xor(deg, off);
        deg = o > deg ? o : deg;
    }
    return deg;
}

// chunked gather-sum: compile-time indices only; dm is wave-uniform.
// pads (index PADR) read the 0.0f sentinel -> sum of reals in ascending order.
__device__ __forceinline__ float r19_gsum(const float* __restrict__ rp,
                                          const int (&iF)[MAXD], int dm) {
    float s = 0.0f;
    s += rp[iF[0]]; s += rp[iF[1]]; s += rp[iF[2]]; s += rp[iF[3]];
    if (dm > 4) {
        s += rp[iF[4]]; s += rp[iF[5]]; s += rp[iF[6]]; s += rp[iF[7]];
        if (dm > 8) {
            s += rp[iF[8]]; s += rp[iF[9]]; s += rp[iF[10]]; s += rp[iF[11]];
            if (dm > 12) {
                s += rp[iF[12]]; s += rp[iF[13]]; s += rp[iF[14]]; s += rp[iF[15]];
                if (dm > 16) {
                    s += rp[iF[16]]; s += rp[iF[17]]; s += rp[iF[18]]; s += rp[iF[19]];
                    if (dm > 20) {
                        s += rp[iF[20]]; s += rp[iF[21]]; s += rp[iF[22]]; s += rp[iF[23]];
                        if (dm > 24) {
                            s += rp[iF[24]]; s += rp[iF[25]]; s += rp[iF[26]]; s += rp[iF[27]];
                        }
                    }
                }
            }
        }
    }
    return s;
}

// chunked gather-OR over uint2 planes (b64 reads).
__device__ __forceinline__ void r19_gor(const uint2* __restrict__ rp,
                                        const int (&iF)[MAXD], int dm, uint2& r) {
    {
        const uint2 v0 = rp[iF[0]], v1 = rp[iF[1]], v2 = rp[iF[2]], v3 = rp[iF[3]];
        r.x |= v0.x | v1.x | v2.x | v3.x;
        r.y |= v0.y | v1.y | v2.y | v3.y;
    }
    if (dm > 4) {
        const uint2 v0 = rp[iF[4]], v1 = rp[iF[5]], v2 = rp[iF[6]], v3 = rp[iF[7]];
        r.x |= v0.x | v1.x | v2.x | v3.x;
        r.y |= v0.y | v1.y | v2.y | v3.y;
        if (dm > 8) {
            const uint2 w0 = rp[iF[8]], w1 = rp[iF[9]], w2 = rp[iF[10]], w3 = rp[iF[11]];
            r.x |= w0.x | w1.x | w2.x | w3.x;
            r.y |= w0.y | w1.y | w2.y | w3.y;
            if (dm > 12) {
                const uint2 u0 = rp[iF[12]], u1 = rp[iF[13]], u2 = rp[iF[14]], u3 = rp[iF[15]];
                r.x |= u0.x | u1.x | u2.x | u3.x;
                r.y |= u0.y | u1.y | u2.y | u3.y;
                if (dm > 16) {
                    const uint2 a0 = rp[iF[16]], a1 = rp[iF[17]], a2 = rp[iF[18]], a3 = rp[iF[19]];
                    r.x |= a0.x | a1.x | a2.x | a3.x;
                    r.y |= a0.y | a1.y | a2.y | a3.y;
                    if (dm > 20) {
                        const uint2 b0 = rp[iF[20]], b1 = rp[iF[21]], b2 = rp[iF[22]], b3 = rp[iF[23]];
                        r.x |= b0.x | b1.x | b2.x | b3.x;
                        r.y |= b0.y | b1.y | b2.y | b3.y;
                        if (dm > 24) {
                            const uint2 c0 = rp[iF[24]], c1 = rp[iF[25]], c2 = rp[iF[26]], c3 = rp[iF[27]];
                            r.x |= c0.x | c1.x | c2.x | c3.x;
                            r.y |= c0.y | c1.y | c2.y | c3.y;
                        }
                    }
                }
            }
        }
    }
}

// ---------------------------------------------------------------------------
// K1: edge scatter -> global bitsets (one edge per thread, 192 blocks).
__global__ __launch_bounds__(256) void r17_scatter(
    const int* __restrict__ ei,
    uint32_t* __restrict__ fwdb, uint32_t* __restrict__ trsb)
{
    const int e = blockIdx.x * 256 + threadIdx.x;
    if (e < EEe) {
        const int src = ei[e], dst = ei[EEe + e];
        atomicOr(&fwdb[(size_t)dst * 16 + ((src & 511) >> 5)], 1u << (src & 31));
        atomicOr(&trsb[(size_t)src * 16 + ((dst & 511) >> 5)], 1u << (dst & 31));
    }
}

// ---------------------------------------------------------------------------
// K2: bitset -> CSR planes (u16, csr[j*8192+node], coalesced stores).
__global__ __launch_bounds__(256) void r17_extract(
    const uint32_t* __restrict__ fwdb, const uint32_t* __restrict__ trsb,
    unsigned short* __restrict__ csrF, unsigned short* __restrict__ csrT)
{
    const int t = blockIdx.x * 256 + threadIdx.x;      // 0..16383
    const int node = t & 8191;
    const uint32_t* bs = (t < 8192) ? (fwdb + (size_t)node * 16)
                                    : (trsb + (size_t)node * 16);
    unsigned short* cs = (t < 8192) ? csrF : csrT;
    int cnt = 0;
    for (int w = 0; w < 16; ++w) {
        uint32_t bits = bs[w];
        while (bits) {
            const int u = (w << 5) + __ffs(bits) - 1;
            bits &= bits - 1;
            if (cnt < MAXD) cs[(size_t)cnt * 8192 + node] = (unsigned short)u;
            ++cnt;
        }
    }
    for (int j = cnt; j < MAXD; ++j) cs[(size_t)j * 8192 + node] = PADR;
}

// ---------------------------------------------------------------------------
// K3: mid, grid (16,12) x 512. y<4: compute planes (dynamic-degree gathers);
// y in 4..11: reachability plane PAIRS via uint2 (b64 gathers).
__global__ __launch_bounds__(512) void r19_mid(
    const float* __restrict__ x,
    const unsigned short* __restrict__ csrF,
    const unsigned short* __restrict__ csrT,
    const float* __restrict__ panw,
    const float* __restrict__ l1w, const float* __restrict__ l1b,
    float* __restrict__ h_raw, float* __restrict__ colsum,
    uint32_t* __restrict__ Rb)
{
    __shared__ __align__(16) uint32_t sbuf[2052];   // 8208 B
    const int b = blockIdx.x, y = blockIdx.y, t = threadIdx.x;
    const int node = b * 512 + t;

    int iF[MAXD];
#pragma unroll
    for (int j = 0; j < MAXD; ++j) iF[j] = (int)csrF[(size_t)j * 8192 + node];
    const int dmF = r19_wmaxdeg(iF);

    if (y < 4) {
        const int c = y;
        float* pa  = (float*)sbuf;             // 513
        float* pb  = (float*)(sbuf + 513);     // 513
        float* wsh = (float*)(sbuf + 1026);    // 21
        if (t < 21) wsh[t] = panw[t];

        pa[t] = 1.0f;
        if (t == 0) { pa[512] = 0.0f; pb[512] = 0.0f; }
        __syncthreads();
        float dacc = wsh[0];
        {
            float* rp = pa; float* rn = pb;
            for (int i = 1; i <= LLp; ++i) {
                const float s = r19_gsum(rp, iF, dmF);
                rn[t] = s;
                dacc += wsh[i] * s;
                __syncthreads();
                float* tp = rp; rp = rn; rn = tp;
            }
        }
        const float d0 = (dacc > 0.0f) ? 1.0f / sqrtf(dacc) : 0.0f;

        int idx[MAXD];
        int dm2;
        if (c == 3) {
#pragma unroll
            for (int j = 0; j < MAXD; ++j) idx[j] = (int)csrT[(size_t)j * 8192 + node];
            dm2 = r19_wmaxdeg(idx);
        } else {
#pragma unroll
            for (int j = 0; j < MAXD; ++j) idx[j] = iF[j];
            dm2 = dmF;
        }
        float seed;
        if (c < 3) {
            float xw = 0.0f;
            const float* xr = x + (size_t)node * NFf;
            for (int f = 0; f < NFf; ++f) xw += xr[f] * l1w[f * 3 + c];
            seed = d0 * xw;
        } else {
            seed = d0;
        }
        pa[t] = seed;
        if (t == 0) { pa[512] = 0.0f; pb[512] = 0.0f; }
        __syncthreads();
        float acc = wsh[0] * seed;
        {
            float* rp = pa; float* rn = pb;
            for (int i = 1; i <= LLp; ++i) {
                const float s = r19_gsum(rp, idx, dm2);
                rn[t] = s;
                acc += wsh[i] * s;
                __syncthreads();
                float* tp = rp; rp = rn; rn = tp;
            }
        }
        if (c < 3) h_raw[(size_t)node * 3 + c] = r17_sane(d0 * acc + l1b[c]);
        else       colsum[node] = r17_sane(d0 * acc);
    } else {
        const int q = y - 4;                   // plane pair {2q, 2q+1}
        uint2* R1 = (uint2*)sbuf;              // 513
        uint2* R2 = R1 + 513;                  // 513
        uint2 seed;
        seed.x = ((t >> 5) == 2 * q)     ? (1u << (t & 31)) : 0u;
        seed.y = ((t >> 5) == 2 * q + 1) ? (1u << (t & 31)) : 0u;
        R1[t] = seed;
        if (t == 0) {
            uint2 z; z.x = 0u; z.y = 0u;
            R1[512] = z; R2[512] = z;
        }
        __syncthreads();
        uint2* Rp = R1; uint2* Rn = R2;
        for (int i = 0; i < LLp; ++i) {
            uint2 r = Rp[t];
            r19_gor(Rp, iF, dmF, r);
            Rn[t] = r;
            __syncthreads();
            uint2* tp = Rp; Rp = Rn; Rn = tp;
        }
        *(uint2*)(&Rb[(size_t)node * 16 + 2 * q]) = Rp[t];
    }
}

// ---------------------------------------------------------------------------
// K4a: pool -- grid 16 x 512. GraphNorm stats + score + top-K rank + staging,
// once per graph. xl staged as float4 for the GAT kernel.
__global__ __launch_bounds__(512) void r19_pool(
    const float* __restrict__ h_raw,
    const float* __restrict__ colsum,
    const uint32_t* __restrict__ Rb,
    const float* n1w, const float* n1b, const float* n1ms,
    const float* poolp, const float* poolb,
    const float* gwl, const float* gbl,
    float* __restrict__ x1,
    float* __restrict__ xpg,      // [BB][KPAD][3]
    float4* __restrict__ xlg,     // [BB][KP2]  (pads zeroed)
    int*   __restrict__ kidxg,    // [BB][KPAD]
    uint32_t* __restrict__ RTg)   // [BB][16][KP2] (pads zeroed)
{
    __shared__ __align__(16) uint32_t pg[2208];
    float* sc   = (float*)pg;                  // 512
    float* mv   = (float*)(pg + 512);          // 8
    float* wred = (float*)(pg + 520);          // 24
    float* xpS  = (float*)(pg + 544);          // 1248 (416*3)
    int*   kidx = (int*)(pg + 1792);           // 416
    const int b = blockIdx.x, t = threadIdx.x;
    const int lane = t & 63, wv = t >> 6;
    const float inv_n = 1.0f / (float)NNt;

    float hv0[16], hv1[16], hv2[16];
    float p0 = 0.0f, p1 = 0.0f, p2 = 0.0f;
#pragma unroll
    for (int k = 0; k < 16; ++k) {
        const float* hr = h_raw + (size_t)(k * 512 + t) * 3;
        hv0[k] = hr[0]; hv1[k] = hr[1]; hv2[k] = hr[2];
        p0 += hv0[k]; p1 += hv1[k]; p2 += hv2[k];
    }
#pragma unroll
    for (int off = 32; off; off >>= 1) {
        p0 += __shfl_xor(p0, off); p1 += __shfl_xor(p1, off); p2 += __shfl_xor(p2, off);
    }
    if (lane == 0) { wred[wv * 3 + 0] = p0; wred[wv * 3 + 1] = p1; wred[wv * 3 + 2] = p2; }
    __syncthreads();
    if (t < 3) {
        float s = 0.0f;
        for (int w = 0; w < 8; ++w) s += wred[w * 3 + t];
        mv[t] = s * inv_n;
    }
    __syncthreads();
    const float mm0 = n1ms[0] * mv[0], mm1 = n1ms[1] * mv[1], mm2 = n1ms[2] * mv[2];
    float q0 = 0.0f, q1 = 0.0f, q2 = 0.0f;
#pragma unroll
    for (int k = 0; k < 16; ++k) {
        const float d0 = hv0[k] - mm0, d1 = hv1[k] - mm1, d2 = hv2[k] - mm2;
        q0 += d0 * d0; q1 += d1 * d1; q2 += d2 * d2;
    }
#pragma unroll
    for (int off = 32; off; off >>= 1) {
        q0 += __shfl_xor(q0, off); q1 += __shfl_xor(q1, off); q2 += __shfl_xor(q2, off);
    }
    if (lane == 0) { wred[wv * 3 + 0] = q0; wred[wv * 3 + 1] = q1; wred[wv * 3 + 2] = q2; }
    __syncthreads();
    if (t < 3) {
        float s = 0.0f;
        for (int w = 0; w < 8; ++w) s += wred[w * 3 + t];
        mv[3 + t] = s * inv_n;
    }
    __syncthreads();

    const float mmv[3] = { mm0, mm1, mm2 };
    float xv[3];
#pragma unroll
    for (int c = 0; c < 3; ++c) {
        const float iv = 1.0f / sqrtf(fmaxf(mv[3 + c], 0.0f) + EPSf);
        const float o  = h_raw[(size_t)(b * NPn + t) * 3 + c] - mmv[c];
        const float tt = n1w[c] * o * iv + n1b[c];
        xv[c] = fmaxf(tt, 0.0f);
        x1[(size_t)(b * NPn + t) * 3 + c] = xv[c];
    }
    float s = poolb[0] * (xv[0] * poolp[0] + xv[1] * poolp[1] + xv[2] * poolp[2])
            + poolb[1] * colsum[b * NPn + t];
    s = tanhf(s);
    if (!(s == s)) s = 0.0f;
    sc[t] = s;
    __syncthreads();

    int cnt = 0;
    for (int u = 0; u < NPn; u += 4) {
        const float4 s4 = *(const float4*)(sc + u);
        cnt += ((s4.x > s) || (s4.x == s && (u + 0) < t)) ? 1 : 0;
        cnt += ((s4.y > s) || (s4.y == s && (u + 1) < t)) ? 1 : 0;
        cnt += ((s4.z > s) || (s4.z == s && (u + 2) < t)) ? 1 : 0;
        cnt += ((s4.w > s) || (s4.w == s && (u + 3) < t)) ? 1 : 0;
    }
    if (cnt < KKk) {                       // rank-count bijection
        const float xp0 = xv[0] * s, xp1 = xv[1] * s, xp2 = xv[2] * s;
        kidx[cnt] = t;
        xpS[cnt * 3 + 0] = xp0;
        xpS[cnt * 3 + 1] = xp1;
        xpS[cnt * 3 + 2] = xp2;
        kidxg[b * KPAD + cnt] = t;
        xpg[(size_t)(b * KPAD + cnt) * 3 + 0] = xp0;
        xpg[(size_t)(b * KPAD + cnt) * 3 + 1] = xp1;
        xpg[(size_t)(b * KPAD + cnt) * 3 + 2] = xp2;
    }
    __syncthreads();

    float Wl[9];
#pragma unroll
    for (int i2 = 0; i2 < 9; ++i2) Wl[i2] = gwl[i2];
    const float Bl0 = gbl[0], Bl1 = gbl[1], Bl2 = gbl[2];
    if (t < KP2) {
        float xl0, xl1, xl2;
        uint32_t* RT = RTg + (size_t)b * 16 * KP2 + t;
        if (t < KKk) {
            const float c0 = xpS[t * 3 + 0];
            const float c1 = xpS[t * 3 + 1];
            const float c2 = xpS[t * 3 + 2];
            xl0 = c0 * Wl[0] + c1 * Wl[3] + c2 * Wl[6] + Bl0;
            xl1 = c0 * Wl[1] + c1 * Wl[4] + c2 * Wl[7] + Bl1;
            xl2 = c0 * Wl[2] + c1 * Wl[5] + c2 * Wl[8] + Bl2;
            const uint4* rr = (const uint4*)(Rb + (size_t)(b * NPn + kidx[t]) * 16);
            const uint4 r0 = rr[0], r1 = rr[1], r2 = rr[2], r3 = rr[3];
            RT[ 0 * KP2] = r0.x; RT[ 1 * KP2] = r0.y; RT[ 2 * KP2] = r0.z; RT[ 3 * KP2] = r0.w;
            RT[ 4 * KP2] = r1.x; RT[ 5 * KP2] = r1.y; RT[ 6 * KP2] = r1.z; RT[ 7 * KP2] = r1.w;
            RT[ 8 * KP2] = r2.x; RT[ 9 * KP2] = r2.y; RT[10 * KP2] = r2.z; RT[11 * KP2] = r2.w;
            RT[12 * KP2] = r3.x; RT[13 * KP2] = r3.y; RT[14 * KP2] = r3.z; RT[15 * KP2] = r3.w;
        } else {
            xl0 = 0.0f; xl1 = 0.0f; xl2 = 0.0f;
#pragma unroll
            for (int w = 0; w < 16; ++w) RT[w * KP2] = 0u;
        }
        xlg[(size_t)(b * KP2 + t)] = make_float4(xl0, xl1, xl2, 0.0f);
    }
}

// ---------------------------------------------------------------------------
// K4b: GAT -- grid (16,52) x 512, one wave per output row, no LDS.
__global__ __launch_bounds__(512) void r19_gat(
    const float* __restrict__ xpg,
    const float4* __restrict__ xlg,
    const int* __restrict__ kidxg,
    const uint32_t* __restrict__ RTg,
    const float* __restrict__ gwr, const float* __restrict__ gbr,
    const float* __restrict__ gatt, const float* __restrict__ gbias,
    float* __restrict__ g_raw)
{
    const int b = blockIdx.x, y = blockIdx.y, t = threadIdx.x;
    const int lane = t & 63, wv = t >> 6;
    const int i = y * 8 + wv;                  // row of this wave
    if (i >= KKk) return;

    float Wr[9];
#pragma unroll
    for (int k = 0; k < 9; ++k) Wr[k] = gwr[k];
    const float Br0 = gbr[0], Br1 = gbr[1], Br2 = gbr[2];
    const float At0 = gatt[0], At1 = gatt[1], At2 = gatt[2];
    const float Gb0 = gbias[0], Gb1 = gbias[1], Gb2 = gbias[2];

    const int bi = kidxg[b * KPAD + i];
    const float c0 = xpg[(size_t)(b * KPAD + i) * 3 + 0];
    const float c1 = xpg[(size_t)(b * KPAD + i) * 3 + 1];
    const float c2 = xpg[(size_t)(b * KPAD + i) * 3 + 2];
    const float xr0 = c0 * Wr[0] + c1 * Wr[3] + c2 * Wr[6] + Br0;
    const float xr1 = c0 * Wr[1] + c1 * Wr[4] + c2 * Wr[7] + Br1;
    const float xr2 = c0 * Wr[2] + c1 * Wr[5] + c2 * Wr[8] + Br2;

    const uint32_t mbit = 1u << (bi & 31);
    const uint32_t* Rw = RTg + (size_t)(b * 16 + (bi >> 5)) * KP2;
    const float4* xlb = xlg + (size_t)b * KP2;

    float mx = -3e38f, lsum = 0.0f, b0 = 0.0f, b1 = 0.0f, b2 = 0.0f;
#pragma unroll
    for (int it = 0; it < 7; ++it) {
        const int j = lane + it * 64;          // < 448, coalesced
        const uint32_t rw = Rw[j];
        const float4 xlv = xlb[j];
        const float xl0 = xlv.x, xl1 = xlv.y, xl2 = xlv.z;
        const bool valid = (rw & mbit) || (j == i);   // pads auto-invalid
        float e0 = xr0 + xl0; e0 = e0 > 0.0f ? e0 : 0.2f * e0;
        float e1 = xr1 + xl1; e1 = e1 > 0.0f ? e1 : 0.2f * e1;
        float e2 = xr2 + xl2; e2 = e2 > 0.0f ? e2 : 0.2f * e2;
        const float sv = At0 * e0 + At1 * e1 + At2 * e2;
        if (valid) {
            if (sv > mx) {
                const float r = __expf(mx - sv);
                lsum *= r; b0 *= r; b1 *= r; b2 *= r;
                mx = sv;
            }
            const float pj = __expf(sv - mx);
            lsum += pj;
            b0 += pj * xl0; b1 += pj * xl1; b2 += pj * xl2;
        }
    }
#pragma unroll
    for (int off = 32; off; off >>= 1) {       // butterfly LSE merge
        const float mo = __shfl_xor(mx, off);
        const float lo = __shfl_xor(lsum, off);
        const float d0 = __shfl_xor(b0, off);
        const float d1 = __shfl_xor(b1, off);
        const float d2 = __shfl_xor(b2, off);
        const float M  = fmaxf(mx, mo);
        const float ea = __expf(mx - M), eb = __expf(mo - M);
        lsum = lsum * ea + lo * eb;
        b0 = b0 * ea + d0 * eb;
        b1 = b1 * ea + d1 * eb;
        b2 = b2 * ea + d2 * eb;
        mx = M;
    }
    if (lane == 0) {
        const float rl = 1.0f / fmaxf(lsum, 1e-30f);
        g_raw[(size_t)(b * KPAD + i) * 3 + 0] = r17_sane(b0 * rl + Gb0);
        g_raw[(size_t)(b * KPAD + i) * 3 + 1] = r17_sane(b1 * rl + Gb1);
        g_raw[(size_t)(b * KPAD + i) * 3 + 2] = r17_sane(b2 * rl + Gb2);
    }
}

// ---------------------------------------------------------------------------
// K5: head (r16 version: shfl stats).
__global__ __launch_bounds__(512) void r17_head(
    const float* __restrict__ g_raw,
    const float* __restrict__ x1,
    const float* __restrict__ x,
    const int* __restrict__ cnid,
    const int* __restrict__ amask,
    const float* n2w, const float* n2b, const float* n2ms,
    const float* v1w, const float* v1b,
    const float* v2w, const float* v2b,
    const float* v3w, const float* v3b,
    const float* a1w, const float* a1b,
    const float* a2w, const float* a2b,
    const float* a3w, const float* a3b,
    float* __restrict__ out)
{
    __shared__ float wred[24];
    __shared__ float mv[6];
    __shared__ float gp[3];
    __shared__ float feat[19];
    __shared__ float h1a[10], h1v[10], h2a[5], h2v[5];
    __shared__ float a3[50];
    __shared__ float vout_s, amean_s;
    const int b = blockIdx.x, t = threadIdx.x;
    const int lane = t & 63, wv = t >> 6;
    const float denom = 1.0f / (float)(BB * KKk);

    float gv0[13], gv1[13], gv2[13];
    float p0 = 0.0f, p1 = 0.0f, p2 = 0.0f;
#pragma unroll
    for (int k = 0; k < 13; ++k) {
        const int r = k * 512 + t;
        float q0 = 0.0f, q1 = 0.0f, q2 = 0.0f;
        if (r < BB * KKk) {
            const int bq = r / KKk, iq = r - bq * KKk;
            const float* gr = g_raw + (size_t)(bq * KPAD + iq) * 3;
            q0 = gr[0]; q1 = gr[1]; q2 = gr[2];
        }
        gv0[k] = q0; gv1[k] = q1; gv2[k] = q2;
        p0 += q0; p1 += q1; p2 += q2;
    }
#pragma unroll
    for (int off = 32; off; off >>= 1) {
        p0 += __shfl_xor(p0, off); p1 += __shfl_xor(p1, off); p2 += __shfl_xor(p2, off);
    }
    if (lane == 0) { wred[wv * 3 + 0] = p0; wred[wv * 3 + 1] = p1; wred[wv * 3 + 2] = p2; }
    __syncthreads();
    if (t < 3) {
        float s = 0.0f;
        for (int w = 0; w < 8; ++w) s += wred[w * 3 + t];
        mv[t] = s * denom;
    }
    __syncthreads();
    const float mm0 = n2ms[0] * mv[0], mm1 = n2ms[1] * mv[1], mm2 = n2ms[2] * mv[2];
    float q0a = 0.0f, q1a = 0.0f, q2a = 0.0f;
#pragma unroll
    for (int k = 0; k < 13; ++k) {
        const int r = k * 512 + t;
        if (r < BB * KKk) {
            const float d0 = gv0[k] - mm0, d1 = gv1[k] - mm1, d2 = gv2[k] - mm2;
            q0a += d0 * d0; q1a += d1 * d1; q2a += d2 * d2;
        }
    }
#pragma unroll
    for (int off = 32; off; off >>= 1) {
        q0a += __shfl_xor(q0a, off); q1a += __shfl_xor(q1a, off); q2a += __shfl_xor(q2a, off);
    }
    if (lane == 0) { wred[wv * 3 + 0] = q0a; wred[wv * 3 + 1] = q1a; wred[wv * 3 + 2] = q2a; }
    __syncthreads();
    if (t < 3) {
        float s = 0.0f;
        for (int w = 0; w < 8; ++w) s += wred[w * 3 + t];
        mv[3 + t] = s * denom;
    }
    __syncthreads();

    const float mmv[3] = { mm0, mm1, mm2 };
    float s3[3] = { 0.0f, 0.0f, 0.0f };
    if (t < KKk) {
        const size_t r = (size_t)(b * KPAD + t) * 3;
#pragma unroll
        for (int c = 0; c < 3; ++c) {
            const float iv = 1.0f / sqrtf(fmaxf(mv[3 + c], 0.0f) + EPSf);
            s3[c] = fmaxf((g_raw[r + c] - mmv[c]) * iv * n2w[c] + n2b[c], 0.0f);
        }
    }
    float g0 = s3[0], g1 = s3[1], g2 = s3[2];
#pragma unroll
    for (int off = 32; off; off >>= 1) {
        g0 += __shfl_xor(g0, off); g1 += __shfl_xor(g1, off); g2 += __shfl_xor(g2, off);
    }
    if (lane == 0) { wred[wv * 3 + 0] = g0; wred[wv * 3 + 1] = g1; wred[wv * 3 + 2] = g2; }
    __syncthreads();
    if (t < 3) {
        float s = 0.0f;
        for (int w = 0; w < 8; ++w) s += wred[w * 3 + t];
        gp[t] = s;
    }
    __syncthreads();

    if (t < 19) {
        const int gidx = cnid[b] + b * KKk;        // faithful: pooled-K offsets
        float fv;
        if (t < 13)      fv = x[(size_t)gidx * NFf + t];
        else if (t < 16) fv = x1[(size_t)gidx * 3 + (t - 13)];
        else             fv = gp[t - 16];
        feat[t] = fv;
    }
    __syncthreads();

    if (t < 10) {
        float s = a1b[t];
        for (int f = 0; f < 19; ++f) s += feat[f] * a1w[f * 10 + t];
        h1a[t] = fmaxf(s, 0.0f);
    } else if (t >= 64 && t < 74) {
        const int j = t - 64;
        float s = v1b[j];
        for (int f = 0; f < 19; ++f) s += feat[f] * v1w[f * 10 + j];
        h1v[j] = fmaxf(s, 0.0f);
    }
    __syncthreads();
    if (t < 5) {
        float s = a2b[t];
        for (int k = 0; k < 10; ++k) s += h1a[k] * a2w[k * 5 + t];
        h2a[t] = fmaxf(s, 0.0f);
    } else if (t >= 64 && t < 69) {
        const int j = t - 64;
        float s = v2b[j];
        for (int k = 0; k < 10; ++k) s += h1v[k] * v2w[k * 5 + j];
        h2v[j] = fmaxf(s, 0.0f);
    }
    __syncthreads();
    if (t < 50) {
        float s = a3b[t];
        for (int k = 0; k < 5; ++k) s += h2a[k] * a3w[k * 50 + t];
        a3[t] = s;
    } else if (t == 64) {
        float s = v3b[0];
        for (int k = 0; k < 5; ++k) s += h2v[k] * v3w[k];
        vout_s = s;
    }
    __syncthreads();
    if (t == 0) {
        float s = 0.0f;
        for (int k = 0; k < 50; ++k) s += a3[k];
        amean_s = s * (1.0f / 50.0f);
    }
    __syncthreads();
    if (t < 50) {
        float q = vout_s + a3[t] - amean_s;
        if (!(q == q)) q = 0.0f;
        q = fminf(fmaxf(q, -QCLMP), QCLMP);
        out[b * NAa + t] = (amask[b * NAa + t] == 0) ? -1e8f : q;   // FP32
    }
}

// ---------------------------------------------------------------------------
extern "C" void kernel_launch(void* const* d_in, const int* in_sizes, int n_in,
                              void* d_out, int out_size, void* d_ws, size_t ws_size,
                              hipStream_t stream) {
    (void)in_sizes; (void)n_in; (void)out_size;
    const float* x     = (const float*)d_in[0];
    const int* ei      = (const int*)d_in[1];
    const int* cnid    = (const int*)d_in[4];
    const int* amask   = (const int*)d_in[5];
    const float* panw  = (const float*)d_in[6];
    const float* l1w   = (const float*)d_in[7];
    const float* l1b   = (const float*)d_in[8];
    const float* n1w   = (const float*)d_in[9];
    const float* n1b   = (const float*)d_in[10];
    const float* n1ms  = (const float*)d_in[11];
    const float* poolp = (const float*)d_in[12];
    const float* poolb = (const float*)d_in[13];
    const float* gwl   = (const float*)d_in[14];
    const float* gbl   = (const float*)d_in[15];
    const float* gwr   = (const float*)d_in[16];
    const float* gbr   = (const float*)d_in[17];
    const float* gatt  = (const float*)d_in[18];
    const float* gbias = (const float*)d_in[19];
    const float* n2w   = (const float*)d_in[20];
    const float* n2b   = (const float*)d_in[21];
    const float* n2ms  = (const float*)d_in[22];
    const float* v1w   = (const float*)d_in[23];
    const float* v1b   = (const float*)d_in[24];
    const float* v2w   = (const float*)d_in[25];
    const float* v2b   = (const float*)d_in[26];
    const float* v3w   = (const float*)d_in[27];
    const float* v3b   = (const float*)d_in[28];
    const float* a1w   = (const float*)d_in[29];
    const float* a1b   = (const float*)d_in[30];
    const float* a2w   = (const float*)d_in[31];
    const float* a2b   = (const float*)d_in[32];
    const float* a3w   = (const float*)d_in[33];
    const float* a3b   = (const float*)d_in[34];
    float* out         = (float*)d_out;

    // ws layout (bytes): fwdb 512K | trsb 512K | Rb 512K | csrF | csrT |
    //                    h_raw | x1 | colsum | g_raw | xpg | xlg(f4) | kidxg | RTg
    uint8_t* wsb = (uint8_t*)d_ws;
    uint32_t* fwdb = (uint32_t*)wsb;
    uint32_t* trsb = (uint32_t*)(wsb + 524288);
    uint32_t* Rb   = (uint32_t*)(wsb + 1048576);
    unsigned short* csrF = (unsigned short*)(wsb + 1572864);
    unsigned short* csrT = csrF + (size_t)MAXD * 8192;
    float* h_raw  = (float*)(csrT + (size_t)MAXD * 8192);
    float* x1     = h_raw + (size_t)NNt * 3;
    float* colsum = x1 + (size_t)NNt * 3;
    float* g_raw  = colsum + NNt;
    float* xpg    = g_raw + (size_t)BB * KPAD * 3;
    float4* xlg   = (float4*)(xpg + (size_t)BB * KPAD * 3);
    int*   kidxg  = (int*)(xlg + (size_t)BB * KP2);
    uint32_t* RTg = (uint32_t*)(kidxg + (size_t)BB * KPAD);
    const size_t needed = 1572864                              // bitsets + Rb
                        + 2 * (size_t)MAXD * 8192 * 2          // csrF + csrT
                        + ((size_t)(2 * NNt * 3 + NNt          // h_raw, x1, colsum
                           + 2 * BB * KPAD * 3)) * 4           // g_raw, xpg
                        + (size_t)BB * KP2 * 16                // xlg (float4)
                        + (size_t)BB * KPAD * 4                // kidxg
                        + (size_t)BB * 16 * KP2 * 4;           // RTg
    if (ws_size < needed) return;

    hipMemsetAsync(fwdb, 0, 1048576, stream);            // both bitsets
    r17_scatter<<<dim3((EEe + 255) / 256), dim3(256), 0, stream>>>(ei, fwdb, trsb);
    r17_extract<<<dim3(64), dim3(256), 0, stream>>>(fwdb, trsb, csrF, csrT);
    r19_mid<<<dim3(16, 12), dim3(512), 0, stream>>>(x, csrF, csrT, panw, l1w, l1b,
                                                    h_raw, colsum, Rb);
    r19_pool<<<dim3(16), dim3(512), 0, stream>>>(h_raw, colsum, Rb,
                                                 n1w, n1b, n1ms, poolp, poolb,
                                                 gwl, gbl,
                                                 x1, xpg, xlg, kidxg, RTg);
    r19_gat<<<dim3(16, 52), dim3(512), 0, stream>>>(xpg, xlg, kidxg, RTg,
                                                    gwr, gbr, gatt, gbias, g_raw);
    r17_head<<<dim3(16), dim3(512), 0, stream>>>(g_raw, x1, x, cnid, amask,
                                                 n2w, n2b, n2ms, v1w, v1b, v2w, v2b, v3w, v3b,
                                                 a1w, a1b, a2w, a2b, a3w, a3b, out);
}